// Round 6
// baseline (222.273 us; speedup 1.0000x reference)
//
#include <hip/hip_runtime.h>
#include <math.h>

// Problem constants (reference: B=4, N=8192, points are [B,N,3] fp32)
#define BATCH 4
#define NPTS 8192
#define BN (BATCH * NPTS)
#define NZB 16                 // 4 searches x 4 batches
#define QK 8                   // queries per lane in the scan
#define QBLK (256 * QK)        // 2048 queries per scan block
#define SUBT 64                // provenance subtile (rescan covers this many)

// Workspace: [0] double acc | [8] uint ticket | [64] int idx_all[NZB*NPTS]
//            [64+512K] float part_d[SPL][NZB*NPTS]
//            [after]   u8    part_t[SPL][NZB*NPTS]  (global subtile id, <128)

__device__ __forceinline__ void pick_ab(int z, const float* pw, const float* pp,
                                        const float* tw, const float* tp,
                                        const float** qa, const float** cb) {
  if (z == 0)      { *qa = pw; *cb = pp; }
  else if (z == 1) { *qa = pp; *cb = pw; }
  else if (z == 2) { *qa = tw; *cb = tp; }
  else             { *qa = tp; *cb = tw; }
}

// ---------------------------------------------------------------------------
// Pass 1: min-distance scan + subtile provenance. VALU-saturated at ~3
// cyc/instr (measured practical ceiling); 3.5 instr/pair structural floor.
// ---------------------------------------------------------------------------
template <int SPL>
__global__ __launch_bounds__(256, 4) void nn_partial_kernel(
    const float* __restrict__ pw, const float* __restrict__ pp,
    const float* __restrict__ tw, const float* __restrict__ tp,
    float* __restrict__ part_d, unsigned char* __restrict__ part_t) {
  constexpr int SLICE = NPTS / SPL;
  constexpr int NSUB = SLICE / SUBT;
  __shared__ float4 sh[SLICE];

  const int zb = blockIdx.z;
  const int z = zb >> 2;
  const int b = zb & 3;
  const float* qa;
  const float* cb;
  pick_ab(z, pw, pp, tw, tp, &qa, &cb);

  const int tid = threadIdx.x;
  const int cslice = blockIdx.y * SLICE;
  const float* cbb = cb + (size_t)b * NPTS * 3;

  // Stage slice as (x,y,z,||b||^2); formulas must match rescan exactly.
  for (int m = tid; m < SLICE; m += 256) {
    const float* c = cbb + (size_t)(cslice + m) * 3;
    const float bx = c[0], by = c[1], bz = c[2];
    sh[m] = make_float4(bx, by, bz, fmaf(bx, bx, fmaf(by, by, bz * bz)));
  }
  __syncthreads();

  const int qbase = blockIdx.x * QBLK;
  float qx[QK], qy[QK], qz[QK], dmin[QK];
  int tile[QK];
  #pragma unroll
  for (int k = 0; k < QK; ++k) {
    const int n = qbase + tid + k * 256;
    const float* q = qa + ((size_t)b * NPTS + n) * 3;
    qx[k] = -2.0f * q[0];
    qy[k] = -2.0f * q[1];
    qz[k] = -2.0f * q[2];
    dmin[k] = INFINITY;
    tile[k] = 0;
  }

  for (int sub = 0; sub < NSUB; ++sub) {
    float pre[QK];
    #pragma unroll
    for (int k = 0; k < QK; ++k) pre[k] = dmin[k];

    const int cb0 = sub * SUBT;
    #pragma unroll 2
    for (int p = 0; p < SUBT / 2; ++p) {
      const float4 c0 = sh[cb0 + 2 * p];
      const float4 c1 = sh[cb0 + 2 * p + 1];
      float t0[QK], t1[QK];
      #pragma unroll
      for (int k = 0; k < QK; ++k)
        t0[k] = fmaf(qx[k], c0.x, fmaf(qy[k], c0.y, fmaf(qz[k], c0.z, c0.w)));
      #pragma unroll
      for (int k = 0; k < QK; ++k)
        t1[k] = fmaf(qx[k], c1.x, fmaf(qy[k], c1.y, fmaf(qz[k], c1.z, c1.w)));
      #pragma unroll
      for (int k = 0; k < QK; ++k)
        dmin[k] = fminf(fminf(t0[k], t1[k]), dmin[k]);   // v_min3_f32
    }
    const int g = blockIdx.y * NSUB + sub;   // global subtile id, [0,128)
    #pragma unroll
    for (int k = 0; k < QK; ++k)
      tile[k] = (dmin[k] < pre[k]) ? g : tile[k];  // strict <: first-min kept
  }

  #pragma unroll
  for (int k = 0; k < QK; ++k) {
    const int n = qbase + tid + k * 256;
    const size_t o = (size_t)blockIdx.y * (NZB * NPTS) + (size_t)zb * NPTS + n;
    part_d[o] = dmin[k];
    part_t[o] = (unsigned char)tile[k];
  }
}

// ---------------------------------------------------------------------------
// Pass 2 (fused): block of 256 handles 256 consecutive queries (one zb).
// Phase A: thread-per-query merge across SPL planes (fully coalesced loads;
//   lexicographic (d, subtile-id) = jnp.argmin first-min) -> LDS.
// Phase B: wave-per-query rescan of the winning 64-candidate subtile
//   (contiguous 768B, bit-identical fma chain); first exact match via
//   __ballot + __ffsll. grid = NZB*NPTS/256 = 512 blocks.
// Also zeroes acc + ticket for the loss dispatch (stream-ordered).
// ---------------------------------------------------------------------------
template <int SPL>
__global__ __launch_bounds__(256) void nn_merge_rescan_kernel(
    const float* __restrict__ pw, const float* __restrict__ pp,
    const float* __restrict__ tw, const float* __restrict__ tp,
    const float* __restrict__ part_d, const unsigned char* __restrict__ part_t,
    int* __restrict__ idx_all, double* __restrict__ acc,
    unsigned int* __restrict__ ticket) {
  __shared__ float sd[256];
  __shared__ int sg[256];

  if (blockIdx.x == 0 && threadIdx.x == 0) { *acc = 0.0; *ticket = 0u; }

  const int tid = threadIdx.x;
  const int qbase = blockIdx.x * 256;
  const int qid = qbase + tid;

  // Phase A: merge split planes (coalesced).
  {
    float best_d = part_d[qid];
    int best_g = part_t[qid];
    #pragma unroll
    for (int s = 1; s < SPL; ++s) {
      const float d = part_d[(size_t)s * (NZB * NPTS) + qid];
      const int g = part_t[(size_t)s * (NZB * NPTS) + qid];
      if (d < best_d || (d == best_d && g < best_g)) { best_d = d; best_g = g; }
    }
    sd[tid] = best_d;
    sg[tid] = best_g;
  }
  __syncthreads();

  // Phase B: wave w rescans local queries [w*64, w*64+64).
  const int zb = qbase >> 13;          // uniform per block (8192 % 256 == 0)
  const int n0 = qbase & (NPTS - 1);
  const int z = zb >> 2;
  const int b = zb & 3;
  const float* qa;
  const float* cb;
  pick_ab(z, pw, pp, tw, tp, &qa, &cb);
  const float* qb0 = qa + (size_t)b * NPTS * 3;
  const float* cbb = cb + (size_t)b * NPTS * 3;

  const int w = tid >> 6;
  const int lane = tid & 63;
  for (int j = 0; j < 64; ++j) {
    const int lq = w * 64 + j;
    const float best_d = sd[lq];       // LDS broadcast
    const int best_g = sg[lq];
    const float* q = qb0 + (size_t)(n0 + lq) * 3;   // wave-uniform 12B
    const float qx = -2.0f * q[0];
    const float qy = -2.0f * q[1];
    const float qz = -2.0f * q[2];
    const int m = best_g * SUBT + lane;             // contiguous across wave
    const float* c = cbb + (size_t)m * 3;
    const float bx = c[0], by = c[1], bz = c[2];
    const float b2 = fmaf(bx, bx, fmaf(by, by, bz * bz));
    const float dd = fmaf(qx, bx, fmaf(qy, by, fmaf(qz, bz, b2)));
    const unsigned long long hit = __ballot(dd == best_d);
    if (lane == 0)
      idx_all[qbase + lq] = best_g * SUBT + (__ffsll((long long)hit) - 1);
  }
}

// ---------------------------------------------------------------------------
// Pass 3: loss (4 MSN terms split across blockIdx.y) + fused finalize via
// atomic ticket: last block to finish reads acc and writes the output.
// loss = 0.25 * (sum of 4 squared-norm sums) / (B*N)
// ---------------------------------------------------------------------------
__device__ __forceinline__ float3 ld3(const float* __restrict__ p, int i) {
  const float* q = p + (size_t)i * 3;
  return make_float3(q[0], q[1], q[2]);
}

__device__ __forceinline__ float diff_nrm2(float3 a1, float3 a2, float3 b1, float3 b2) {
  const float x = (a1.x - a2.x) - (b1.x - b2.x);
  const float y = (a1.y - a2.y) - (b1.y - b2.y);
  const float z = (a1.z - a2.z) - (b1.z - b2.z);
  return fmaf(x, x, fmaf(y, y, z * z));
}

__global__ __launch_bounds__(256) void loss_final_kernel(
    const float* __restrict__ pw, const float* __restrict__ pp,
    const float* __restrict__ tw, const float* __restrict__ tp,
    const int* __restrict__ ipw, const int* __restrict__ itw,
    const int* __restrict__ ipp, const int* __restrict__ itp,
    const int* __restrict__ idx_all, double* __restrict__ acc,
    unsigned int* __restrict__ ticket, float* __restrict__ out) {
  const int gid = blockIdx.x * 256 + threadIdx.x;  // [0, B*N)
  const int term = blockIdx.y;
  const int b = gid >> 13;
  const int n = gid & (NPTS - 1);
  const int base = b * NPTS;

  const float* PW = pw + (size_t)base * 3;
  const float* PP = pp + (size_t)base * 3;
  const float* TW = tw + (size_t)base * 3;
  const float* TP = tp + (size_t)base * 3;
  const int* I1P = idx_all + (0 * BATCH + b) * NPTS;  // NN pial for white (pred)
  const int* I2P = idx_all + (1 * BATCH + b) * NPTS;  // NN white for pial (pred)
  const int* I1T = idx_all + (2 * BATCH + b) * NPTS;  // NN pial for white (true)
  const int* I2T = idx_all + (3 * BATCH + b) * NPTS;  // NN white for pial (true)

  float sv;
  if (term == 0) {        // msn(yp_inner, yt_inner[i_pred_white])
    const int j = ipw[base + n];
    sv = diff_nrm2(ld3(PP, I1P[n]), ld3(PW, n), ld3(TP, I1T[j]), ld3(TW, j));
  } else if (term == 1) { // msn(yp_inner[i_true_white], yt_inner)
    const int k = itw[base + n];
    sv = diff_nrm2(ld3(PP, I1P[k]), ld3(PW, k), ld3(TP, I1T[n]), ld3(TW, n));
  } else if (term == 2) { // msn(yp_outer, yt_outer[i_pred_pial])
    const int j = ipp[base + n];
    sv = diff_nrm2(ld3(PP, n), ld3(PW, I2P[n]), ld3(TP, j), ld3(TW, I2T[j]));
  } else {                // msn(yp_outer[i_true_pial], yt_outer)
    const int k = itp[base + n];
    sv = diff_nrm2(ld3(PP, k), ld3(PW, I2P[k]), ld3(TP, n), ld3(TW, I2T[n]));
  }

  double ds = (double)sv;
  #pragma unroll
  for (int o = 32; o > 0; o >>= 1) ds += __shfl_down(ds, o, 64);
  if ((threadIdx.x & 63) == 0) atomicAdd(acc, ds);

  __threadfence();     // order this block's acc adds before its ticket bump
  __syncthreads();
  if (threadIdx.x == 0) {
    const unsigned int total = gridDim.x * gridDim.y;
    const unsigned int old = atomicAdd(ticket, 1u);
    if (old == total - 1u) {
      const double t = atomicAdd(acc, 0.0);   // atomic read of the full sum
      out[0] = (float)(0.25 * t / (double)BN);
    }
  }
}

// ---------------------------------------------------------------------------
template <int SPL>
static void run_pipeline(const float* pw, const float* pp, const float* tw,
                         const float* tp, const int* ipw, const int* itw,
                         const int* ipp, const int* itp, char* ws, float* out,
                         hipStream_t stream) {
  double* acc = (double*)ws;
  unsigned int* ticket = (unsigned int*)(ws + 8);
  int* idx_all = (int*)(ws + 64);
  float* part_d = (float*)(ws + 64 + (size_t)NZB * NPTS * 4);
  unsigned char* part_t =
      (unsigned char*)(ws + 64 + (size_t)NZB * NPTS * 4 +
                       (size_t)SPL * NZB * NPTS * 4);

  dim3 grid_nn(NPTS / QBLK, SPL, NZB);
  nn_partial_kernel<SPL><<<grid_nn, 256, 0, stream>>>(pw, pp, tw, tp, part_d,
                                                      part_t);
  nn_merge_rescan_kernel<SPL><<<(NZB * NPTS) / 256, 256, 0, stream>>>(
      pw, pp, tw, tp, part_d, part_t, idx_all, acc, ticket);

  dim3 grid_loss(BN / 256, 4);
  loss_final_kernel<<<grid_loss, 256, 0, stream>>>(
      pw, pp, tw, tp, ipw, itw, ipp, itp, idx_all, acc, ticket, out);
}

extern "C" void kernel_launch(void* const* d_in, const int* in_sizes, int n_in,
                              void* d_out, int out_size, void* d_ws, size_t ws_size,
                              hipStream_t stream) {
  const float* pw = (const float*)d_in[0];
  const float* pp = (const float*)d_in[1];
  const float* tw = (const float*)d_in[2];
  const float* tp = (const float*)d_in[3];
  const int* ipw = (const int*)d_in[4];
  const int* itw = (const int*)d_in[5];
  const int* ipp = (const int*)d_in[6];
  const int* itp = (const int*)d_in[7];
  char* ws = (char*)d_ws;
  float* out = (float*)d_out;

  // ws need per SPL: 64 + idx(512K) + part_d(SPL*512K) + part_t(SPL*128K)
  const size_t base_need = 64 + (size_t)NZB * NPTS * 4;
  const size_t per_spl = (size_t)NZB * NPTS * 5;
  if (ws_size >= base_need + 32 * per_spl) {
    run_pipeline<32>(pw, pp, tw, tp, ipw, itw, ipp, itp, ws, out, stream);
  } else if (ws_size >= base_need + 16 * per_spl) {
    run_pipeline<16>(pw, pp, tw, tp, ipw, itw, ipp, itp, ws, out, stream);
  } else {
    run_pipeline<8>(pw, pp, tw, tp, ipw, itw, ipp, itp, ws, out, stream);
  }
}

// Round 7
// 213.919 us; speedup vs baseline: 1.0391x; 1.0391x over previous
//
#include <hip/hip_runtime.h>
#include <math.h>

// Problem constants (reference: B=4, N=8192, points are [B,N,3] fp32)
#define BATCH 4
#define NPTS 8192
#define BN (BATCH * NPTS)
#define NZB 16                 // 4 searches x 4 batches
#define QK 16                  // queries per lane in the scan (2x LDS reuse)
#define QBLK (256 * QK)        // 4096 queries per scan block

// Workspace: [0] double acc | [64] int idx_all[NZB*NPTS] (512KB)
//            [+512K] u8 best_s[NZB*NPTS] (128KB)
//            [+128K] float part_d[SPL][NZB*NPTS] (SPL*512KB)

__device__ __forceinline__ void pick_ab(int z, const float* pw, const float* pp,
                                        const float* tw, const float* tp,
                                        const float** qa, const float** cb) {
  if (z == 0)      { *qa = pw; *cb = pp; }
  else if (z == 1) { *qa = pp; *cb = pw; }
  else if (z == 2) { *qa = tw; *cb = tp; }
  else             { *qa = tp; *cb = tw; }
}

// ---------------------------------------------------------------------------
// Pass 1: min-distance scan, NO index/tile bookkeeping (min registers, max
// LDS reuse). d(q,m) = ||b_m||^2 - 2 q.b_m (3 fma); min3 merges pairs.
// QK=16: one ds_read_b128 feeds 16 queries -> LDS pipe demand ~43%.
// grid = (NPTS/QBLK=2, SPL, NZB), block = 256.
// ---------------------------------------------------------------------------
template <int SPL>
__global__ __launch_bounds__(256, 4) void nn_partial_kernel(
    const float* __restrict__ pw, const float* __restrict__ pp,
    const float* __restrict__ tw, const float* __restrict__ tp,
    float* __restrict__ part_d) {
  constexpr int SLICE = NPTS / SPL;
  __shared__ float4 sh[SLICE];

  const int zb = blockIdx.z;
  const int z = zb >> 2;
  const int b = zb & 3;
  const float* qa;
  const float* cb;
  pick_ab(z, pw, pp, tw, tp, &qa, &cb);

  const int tid = threadIdx.x;
  const int cslice = blockIdx.y * SLICE;
  const float* cbb = cb + (size_t)b * NPTS * 3;

  // Stage slice as (x,y,z,||b||^2); formulas must match rescan exactly.
  for (int m = tid; m < SLICE; m += 256) {
    const float* c = cbb + (size_t)(cslice + m) * 3;
    const float bx = c[0], by = c[1], bz = c[2];
    sh[m] = make_float4(bx, by, bz, fmaf(bx, bx, fmaf(by, by, bz * bz)));
  }
  __syncthreads();

  const int qbase = blockIdx.x * QBLK;
  float qx[QK], qy[QK], qz[QK], dmin[QK];
  #pragma unroll
  for (int k = 0; k < QK; ++k) {
    const int n = qbase + tid + k * 256;
    const float* q = qa + ((size_t)b * NPTS + n) * 3;
    qx[k] = -2.0f * q[0];
    qy[k] = -2.0f * q[1];
    qz[k] = -2.0f * q[2];
    dmin[k] = INFINITY;
  }

  #pragma unroll 2
  for (int p = 0; p < SLICE / 2; ++p) {
    const float4 c0 = sh[2 * p];
    const float4 c1 = sh[2 * p + 1];
    #pragma unroll
    for (int k = 0; k < QK; ++k) {
      const float t0 = fmaf(qx[k], c0.x, fmaf(qy[k], c0.y, fmaf(qz[k], c0.z, c0.w)));
      const float t1 = fmaf(qx[k], c1.x, fmaf(qy[k], c1.y, fmaf(qz[k], c1.z, c1.w)));
      dmin[k] = fminf(fminf(t0, t1), dmin[k]);   // v_min3_f32
    }
  }

  #pragma unroll
  for (int k = 0; k < QK; ++k) {
    const int n = qbase + tid + k * 256;
    part_d[(size_t)blockIdx.y * (NZB * NPTS) + (size_t)zb * NPTS + n] = dmin[k];
  }
}

// ---------------------------------------------------------------------------
// Pass 2a: merge splits, THREAD per query, fully coalesced. Strict '<' in
// ascending split order keeps the EARLIEST split achieving the min — the
// split containing the global first-min candidate (jnp.argmin semantics).
// Writes merged d to plane 0 and winning split id to best_s.
// ---------------------------------------------------------------------------
template <int SPL>
__global__ __launch_bounds__(256) void nn_merge_kernel(
    float* __restrict__ part_d, unsigned char* __restrict__ best_s,
    double* __restrict__ acc) {
  if (blockIdx.x == 0 && threadIdx.x == 0) *acc = 0.0;  // before loss dispatch

  const int qid = blockIdx.x * 256 + threadIdx.x;  // [0, NZB*NPTS)
  float bd = part_d[qid];
  int bs = 0;
  #pragma unroll
  for (int s = 1; s < SPL; ++s) {
    const float d = part_d[(size_t)s * (NZB * NPTS) + qid];
    if (d < bd) { bd = d; bs = s; }   // strict <: earliest split kept
  }
  part_d[qid] = bd;
  best_s[qid] = (unsigned char)bs;
}

// ---------------------------------------------------------------------------
// Pass 2b: rescan, WAVE per query. 64 lanes sweep the winning split's SLICE
// candidates (SLICE/64 independent contiguous 768B loads, bit-identical fma
// chain); int-min-reduce the smallest exact match = first-min index.
// block = 1024 (16 waves), grid = NZB*NPTS/16.
// ---------------------------------------------------------------------------
template <int SPL>
__global__ __launch_bounds__(1024) void nn_rescan_kernel(
    const float* __restrict__ pw, const float* __restrict__ pp,
    const float* __restrict__ tw, const float* __restrict__ tp,
    const float* __restrict__ part_d, const unsigned char* __restrict__ best_s,
    int* __restrict__ idx_all) {
  constexpr int SLICE = NPTS / SPL;
  const int qid = (blockIdx.x * 1024 + threadIdx.x) >> 6;  // [0, NZB*NPTS)
  const int lane = threadIdx.x & 63;
  const int zb = qid >> 13;
  const int n = qid & (NPTS - 1);
  const int z = zb >> 2;
  const int b = zb & 3;
  const float* qa;
  const float* cb;
  pick_ab(z, pw, pp, tw, tp, &qa, &cb);

  const float best_d = part_d[qid];            // wave-uniform: broadcast
  const int base = (int)best_s[qid] * SLICE;

  const float* q = qa + ((size_t)b * NPTS + n) * 3;
  const float qx = -2.0f * q[0];
  const float qy = -2.0f * q[1];
  const float qz = -2.0f * q[2];
  const float* cbb = cb + (size_t)b * NPTS * 3;

  int best_i = 0x7fffffff;
  #pragma unroll
  for (int j = 0; j < SLICE / 64; ++j) {       // independent loads
    const int m = base + j * 64 + lane;
    const float* c = cbb + (size_t)m * 3;
    const float bx = c[0], by = c[1], bz = c[2];
    const float b2 = fmaf(bx, bx, fmaf(by, by, bz * bz));
    const float dd = fmaf(qx, bx, fmaf(qy, by, fmaf(qz, bz, b2)));
    if (dd == best_d) best_i = min(best_i, m);
  }
  #pragma unroll
  for (int off = 32; off > 0; off >>= 1)
    best_i = min(best_i, __shfl_down(best_i, off));
  if (lane == 0) idx_all[qid] = best_i;
}

// ---------------------------------------------------------------------------
// Pass 3: loss (4 MSN terms split across blockIdx.y), then tiny finalize.
// loss = 0.25 * (sum of 4 squared-norm sums) / (B*N)
// ---------------------------------------------------------------------------
__device__ __forceinline__ float3 ld3(const float* __restrict__ p, int i) {
  const float* q = p + (size_t)i * 3;
  return make_float3(q[0], q[1], q[2]);
}

__device__ __forceinline__ float diff_nrm2(float3 a1, float3 a2, float3 b1, float3 b2) {
  const float x = (a1.x - a2.x) - (b1.x - b2.x);
  const float y = (a1.y - a2.y) - (b1.y - b2.y);
  const float z = (a1.z - a2.z) - (b1.z - b2.z);
  return fmaf(x, x, fmaf(y, y, z * z));
}

__global__ __launch_bounds__(256) void loss_kernel(
    const float* __restrict__ pw, const float* __restrict__ pp,
    const float* __restrict__ tw, const float* __restrict__ tp,
    const int* __restrict__ ipw, const int* __restrict__ itw,
    const int* __restrict__ ipp, const int* __restrict__ itp,
    const int* __restrict__ idx_all, double* __restrict__ acc) {
  const int gid = blockIdx.x * 256 + threadIdx.x;  // [0, B*N)
  const int term = blockIdx.y;
  const int b = gid >> 13;
  const int n = gid & (NPTS - 1);
  const int base = b * NPTS;

  const float* PW = pw + (size_t)base * 3;
  const float* PP = pp + (size_t)base * 3;
  const float* TW = tw + (size_t)base * 3;
  const float* TP = tp + (size_t)base * 3;
  const int* I1P = idx_all + (0 * BATCH + b) * NPTS;  // NN pial for white (pred)
  const int* I2P = idx_all + (1 * BATCH + b) * NPTS;  // NN white for pial (pred)
  const int* I1T = idx_all + (2 * BATCH + b) * NPTS;  // NN pial for white (true)
  const int* I2T = idx_all + (3 * BATCH + b) * NPTS;  // NN white for pial (true)

  float sv;
  if (term == 0) {        // msn(yp_inner, yt_inner[i_pred_white])
    const int j = ipw[base + n];
    sv = diff_nrm2(ld3(PP, I1P[n]), ld3(PW, n), ld3(TP, I1T[j]), ld3(TW, j));
  } else if (term == 1) { // msn(yp_inner[i_true_white], yt_inner)
    const int k = itw[base + n];
    sv = diff_nrm2(ld3(PP, I1P[k]), ld3(PW, k), ld3(TP, I1T[n]), ld3(TW, n));
  } else if (term == 2) { // msn(yp_outer, yt_outer[i_pred_pial])
    const int j = ipp[base + n];
    sv = diff_nrm2(ld3(PP, n), ld3(PW, I2P[n]), ld3(TP, j), ld3(TW, I2T[j]));
  } else {                // msn(yp_outer[i_true_pial], yt_outer)
    const int k = itp[base + n];
    sv = diff_nrm2(ld3(PP, k), ld3(PW, I2P[k]), ld3(TP, n), ld3(TW, I2T[n]));
  }

  double ds = (double)sv;
  #pragma unroll
  for (int o = 32; o > 0; o >>= 1) ds += __shfl_down(ds, o, 64);
  if ((threadIdx.x & 63) == 0) atomicAdd(acc, ds);
}

__global__ void finalize_kernel(const double* __restrict__ acc,
                                float* __restrict__ out) {
  out[0] = (float)(0.25 * (*acc) / (double)BN);
}

// ---------------------------------------------------------------------------
template <int SPL>
static void run_pipeline(const float* pw, const float* pp, const float* tw,
                         const float* tp, const int* ipw, const int* itw,
                         const int* ipp, const int* itp, char* ws, float* out,
                         hipStream_t stream) {
  double* acc = (double*)ws;
  int* idx_all = (int*)(ws + 64);
  unsigned char* best_s = (unsigned char*)(ws + 64 + (size_t)NZB * NPTS * 4);
  float* part_d = (float*)(ws + 64 + (size_t)NZB * NPTS * 5);

  dim3 grid_nn(NPTS / QBLK, SPL, NZB);
  nn_partial_kernel<SPL><<<grid_nn, 256, 0, stream>>>(pw, pp, tw, tp, part_d);
  nn_merge_kernel<SPL><<<(NZB * NPTS) / 256, 256, 0, stream>>>(part_d, best_s,
                                                               acc);
  nn_rescan_kernel<SPL><<<(NZB * NPTS) / 16, 1024, 0, stream>>>(
      pw, pp, tw, tp, part_d, best_s, idx_all);

  dim3 grid_loss(BN / 256, 4);
  loss_kernel<<<grid_loss, 256, 0, stream>>>(pw, pp, tw, tp, ipw, itw, ipp, itp,
                                             idx_all, acc);
  finalize_kernel<<<1, 1, 0, stream>>>(acc, out);
}

extern "C" void kernel_launch(void* const* d_in, const int* in_sizes, int n_in,
                              void* d_out, int out_size, void* d_ws, size_t ws_size,
                              hipStream_t stream) {
  const float* pw = (const float*)d_in[0];
  const float* pp = (const float*)d_in[1];
  const float* tw = (const float*)d_in[2];
  const float* tp = (const float*)d_in[3];
  const int* ipw = (const int*)d_in[4];
  const int* itw = (const int*)d_in[5];
  const int* ipp = (const int*)d_in[6];
  const int* itp = (const int*)d_in[7];
  char* ws = (char*)d_ws;
  float* out = (float*)d_out;

  // ws need: 64 + idx(512K) + best_s(128K) + part_d(SPL*512K)
  const size_t base_need = 64 + (size_t)NZB * NPTS * 5;
  const size_t per_spl = (size_t)NZB * NPTS * 4;
  if (ws_size >= base_need + 32 * per_spl) {
    run_pipeline<32>(pw, pp, tw, tp, ipw, itw, ipp, itp, ws, out, stream);
  } else if (ws_size >= base_need + 16 * per_spl) {
    run_pipeline<16>(pw, pp, tw, tp, ipw, itw, ipp, itp, ws, out, stream);
  } else {
    run_pipeline<8>(pw, pp, tw, tp, ipw, itw, ipp, itp, ws, out, stream);
  }
}

// Round 8
// 197.824 us; speedup vs baseline: 1.1236x; 1.0814x over previous
//
#include <hip/hip_runtime.h>
#include <math.h>

// Problem constants (reference: B=4, N=8192, points are [B,N,3] fp32)
#define BATCH 4
#define NPTS 8192
#define BN (BATCH * NPTS)
#define NZB 16                 // 4 searches x 4 batches
#define QK 8                   // queries per lane in the scan
#define QBLK (256 * QK)        // 2048 queries per scan block
#define SUBT 64                // provenance subtile (rescan covers this many)

// Workspace: [0] double acc | [64] int idx_all[NZB*NPTS] (512KB)
//            [64+512K] float part_d[SPL][NZB*NPTS]
//            [after]   u8    part_t[SPL][NZB*NPTS]  (global subtile id, <128)

__device__ __forceinline__ void pick_ab(int z, const float* pw, const float* pp,
                                        const float* tw, const float* tp,
                                        const float** qa, const float** cb) {
  if (z == 0)      { *qa = pw; *cb = pp; }
  else if (z == 1) { *qa = pp; *cb = pw; }
  else if (z == 2) { *qa = tw; *cb = tp; }
  else             { *qa = tp; *cb = tw; }
}

// ---------------------------------------------------------------------------
// Pass 1 (R5-proven, 83.5us): min-distance scan + subtile provenance.
// At ~3.6 cyc/wave-instr vs measured practical fp32 issue ~3.05 — near the
// VALU ceiling for this formulation.
// ---------------------------------------------------------------------------
template <int SPL>
__global__ __launch_bounds__(256, 4) void nn_partial_kernel(
    const float* __restrict__ pw, const float* __restrict__ pp,
    const float* __restrict__ tw, const float* __restrict__ tp,
    float* __restrict__ part_d, unsigned char* __restrict__ part_t) {
  constexpr int SLICE = NPTS / SPL;
  constexpr int NSUB = SLICE / SUBT;
  __shared__ float4 sh[SLICE];

  const int zb = blockIdx.z;
  const int z = zb >> 2;
  const int b = zb & 3;
  const float* qa;
  const float* cb;
  pick_ab(z, pw, pp, tw, tp, &qa, &cb);

  const int tid = threadIdx.x;
  const int cslice = blockIdx.y * SLICE;
  const float* cbb = cb + (size_t)b * NPTS * 3;

  // Stage slice as (x,y,z,||b||^2); formulas must match rescan exactly.
  for (int m = tid; m < SLICE; m += 256) {
    const float* c = cbb + (size_t)(cslice + m) * 3;
    const float bx = c[0], by = c[1], bz = c[2];
    sh[m] = make_float4(bx, by, bz, fmaf(bx, bx, fmaf(by, by, bz * bz)));
  }
  __syncthreads();

  const int qbase = blockIdx.x * QBLK;
  float qx[QK], qy[QK], qz[QK], dmin[QK];
  int tile[QK];
  #pragma unroll
  for (int k = 0; k < QK; ++k) {
    const int n = qbase + tid + k * 256;
    const float* q = qa + ((size_t)b * NPTS + n) * 3;
    qx[k] = -2.0f * q[0];
    qy[k] = -2.0f * q[1];
    qz[k] = -2.0f * q[2];
    dmin[k] = INFINITY;
    tile[k] = 0;
  }

  for (int sub = 0; sub < NSUB; ++sub) {
    float pre[QK];
    #pragma unroll
    for (int k = 0; k < QK; ++k) pre[k] = dmin[k];

    const int cb0 = sub * SUBT;
    #pragma unroll 2
    for (int p = 0; p < SUBT / 2; ++p) {
      const float4 c0 = sh[cb0 + 2 * p];
      const float4 c1 = sh[cb0 + 2 * p + 1];
      float t0[QK], t1[QK];
      #pragma unroll
      for (int k = 0; k < QK; ++k)
        t0[k] = fmaf(qx[k], c0.x, fmaf(qy[k], c0.y, fmaf(qz[k], c0.z, c0.w)));
      #pragma unroll
      for (int k = 0; k < QK; ++k)
        t1[k] = fmaf(qx[k], c1.x, fmaf(qy[k], c1.y, fmaf(qz[k], c1.z, c1.w)));
      #pragma unroll
      for (int k = 0; k < QK; ++k)
        dmin[k] = fminf(fminf(t0[k], t1[k]), dmin[k]);   // v_min3_f32
    }
    const int g = blockIdx.y * NSUB + sub;   // global subtile id, [0,128)
    #pragma unroll
    for (int k = 0; k < QK; ++k)
      tile[k] = (dmin[k] < pre[k]) ? g : tile[k];  // strict <: first-min kept
  }

  #pragma unroll
  for (int k = 0; k < QK; ++k) {
    const int n = qbase + tid + k * 256;
    const size_t o = (size_t)blockIdx.y * (NZB * NPTS) + (size_t)zb * NPTS + n;
    part_d[o] = dmin[k];
    part_t[o] = (unsigned char)tile[k];
  }
}

// ---------------------------------------------------------------------------
// Pass 2 (fused merge + rescan, one dispatch). Block = 1024 (16 waves)
// covers 64 consecutive queries (one zb; 64 | 8192).
//   Merge: wave v lexmin-merges planes {v, v+16, ...} with fully-coalesced
//     64-consecutive-float loads -> LDS[16][64]; wave 0 reduces the 16
//     partials per query (lexicographic (d, subtile) = jnp.argmin first-min).
//   Rescan: wave v handles queries v*4..v*4+3: 64 lanes check the winning
//     64-candidate subtile (contiguous 768B, bit-identical fma chain);
//     __ballot + __ffsll picks the smallest matching index.
// grid = NZB*NPTS/64 = 2048 blocks. Also zeroes acc for the loss dispatch.
// ---------------------------------------------------------------------------
template <int SPL>
__global__ __launch_bounds__(1024) void nn_merge_rescan_kernel(
    const float* __restrict__ pw, const float* __restrict__ pp,
    const float* __restrict__ tw, const float* __restrict__ tp,
    const float* __restrict__ part_d, const unsigned char* __restrict__ part_t,
    int* __restrict__ idx_all, double* __restrict__ acc) {
  __shared__ float md[16][64];
  __shared__ int mg[16][64];
  __shared__ float sdq[64];
  __shared__ int sgq[64];

  if (blockIdx.x == 0 && threadIdx.x == 0) *acc = 0.0;

  const int tid = threadIdx.x;
  const int wv = tid >> 6;          // wave id, 0..15
  const int lane = tid & 63;
  const int qid0 = blockIdx.x * 64;

  // --- Merge phase: coalesced plane loads, per-wave partial lexmin ---
  {
    float bd = INFINITY;
    int bg = 0x7fffffff;
    for (int s = wv; s < SPL; s += 16) {
      const size_t o = (size_t)s * (NZB * NPTS) + qid0 + lane;  // 64 consecutive
      const float d = part_d[o];
      const int g = part_t[o];
      if (d < bd || (d == bd && g < bg)) { bd = d; bg = g; }
    }
    md[wv][lane] = bd;
    mg[wv][lane] = bg;
  }
  __syncthreads();
  if (wv == 0) {                    // wave 0: final 16-way reduce per query
    float bd = md[0][lane];
    int bg = mg[0][lane];
    #pragma unroll
    for (int v = 1; v < 16; ++v) {
      const float d = md[v][lane];
      const int g = mg[v][lane];
      if (d < bd || (d == bd && g < bg)) { bd = d; bg = g; }
    }
    sdq[lane] = bd;
    sgq[lane] = bg;
  }
  __syncthreads();

  // --- Rescan phase: wave v -> queries v*4 .. v*4+3 ---
  const int zb = qid0 >> 13;        // uniform per block
  const int z = zb >> 2;
  const int b = zb & 3;
  const float* qa;
  const float* cb;
  pick_ab(z, pw, pp, tw, tp, &qa, &cb);
  const float* qb0 = qa + (size_t)b * NPTS * 3;
  const float* cbb = cb + (size_t)b * NPTS * 3;
  const int n0 = qid0 & (NPTS - 1);

  #pragma unroll
  for (int j = 0; j < 4; ++j) {
    const int lq = wv * 4 + j;
    const float best_d = sdq[lq];   // LDS broadcast
    const int best_g = sgq[lq];
    const float* q = qb0 + (size_t)(n0 + lq) * 3;   // wave-uniform 12B
    const float qx = -2.0f * q[0];
    const float qy = -2.0f * q[1];
    const float qz = -2.0f * q[2];
    const int m = best_g * SUBT + lane;             // contiguous across wave
    const float* c = cbb + (size_t)m * 3;
    const float bx = c[0], by = c[1], bz = c[2];
    const float b2 = fmaf(bx, bx, fmaf(by, by, bz * bz));
    const float dd = fmaf(qx, bx, fmaf(qy, by, fmaf(qz, bz, b2)));
    const unsigned long long hit = __ballot(dd == best_d);
    if (lane == 0)
      idx_all[qid0 + lq] = best_g * SUBT + (__ffsll((long long)hit) - 1);
  }
}

// ---------------------------------------------------------------------------
// Pass 3: loss (4 MSN terms split across blockIdx.y), then tiny finalize.
// loss = 0.25 * (sum of 4 squared-norm sums) / (B*N)
// ---------------------------------------------------------------------------
__device__ __forceinline__ float3 ld3(const float* __restrict__ p, int i) {
  const float* q = p + (size_t)i * 3;
  return make_float3(q[0], q[1], q[2]);
}

__device__ __forceinline__ float diff_nrm2(float3 a1, float3 a2, float3 b1, float3 b2) {
  const float x = (a1.x - a2.x) - (b1.x - b2.x);
  const float y = (a1.y - a2.y) - (b1.y - b2.y);
  const float z = (a1.z - a2.z) - (b1.z - b2.z);
  return fmaf(x, x, fmaf(y, y, z * z));
}

__global__ __launch_bounds__(256) void loss_kernel(
    const float* __restrict__ pw, const float* __restrict__ pp,
    const float* __restrict__ tw, const float* __restrict__ tp,
    const int* __restrict__ ipw, const int* __restrict__ itw,
    const int* __restrict__ ipp, const int* __restrict__ itp,
    const int* __restrict__ idx_all, double* __restrict__ acc) {
  const int gid = blockIdx.x * 256 + threadIdx.x;  // [0, B*N)
  const int term = blockIdx.y;
  const int b = gid >> 13;
  const int n = gid & (NPTS - 1);
  const int base = b * NPTS;

  const float* PW = pw + (size_t)base * 3;
  const float* PP = pp + (size_t)base * 3;
  const float* TW = tw + (size_t)base * 3;
  const float* TP = tp + (size_t)base * 3;
  const int* I1P = idx_all + (0 * BATCH + b) * NPTS;  // NN pial for white (pred)
  const int* I2P = idx_all + (1 * BATCH + b) * NPTS;  // NN white for pial (pred)
  const int* I1T = idx_all + (2 * BATCH + b) * NPTS;  // NN pial for white (true)
  const int* I2T = idx_all + (3 * BATCH + b) * NPTS;  // NN white for pial (true)

  float sv;
  if (term == 0) {        // msn(yp_inner, yt_inner[i_pred_white])
    const int j = ipw[base + n];
    sv = diff_nrm2(ld3(PP, I1P[n]), ld3(PW, n), ld3(TP, I1T[j]), ld3(TW, j));
  } else if (term == 1) { // msn(yp_inner[i_true_white], yt_inner)
    const int k = itw[base + n];
    sv = diff_nrm2(ld3(PP, I1P[k]), ld3(PW, k), ld3(TP, I1T[n]), ld3(TW, n));
  } else if (term == 2) { // msn(yp_outer, yt_outer[i_pred_pial])
    const int j = ipp[base + n];
    sv = diff_nrm2(ld3(PP, n), ld3(PW, I2P[n]), ld3(TP, j), ld3(TW, I2T[j]));
  } else {                // msn(yp_outer[i_true_pial], yt_outer)
    const int k = itp[base + n];
    sv = diff_nrm2(ld3(PP, k), ld3(PW, I2P[k]), ld3(TP, n), ld3(TW, I2T[n]));
  }

  double ds = (double)sv;
  #pragma unroll
  for (int o = 32; o > 0; o >>= 1) ds += __shfl_down(ds, o, 64);
  if ((threadIdx.x & 63) == 0) atomicAdd(acc, ds);
}

__global__ void finalize_kernel(const double* __restrict__ acc,
                                float* __restrict__ out) {
  out[0] = (float)(0.25 * (*acc) / (double)BN);
}

// ---------------------------------------------------------------------------
template <int SPL>
static void run_pipeline(const float* pw, const float* pp, const float* tw,
                         const float* tp, const int* ipw, const int* itw,
                         const int* ipp, const int* itp, char* ws, float* out,
                         hipStream_t stream) {
  double* acc = (double*)ws;
  int* idx_all = (int*)(ws + 64);
  float* part_d = (float*)(ws + 64 + (size_t)NZB * NPTS * 4);
  unsigned char* part_t =
      (unsigned char*)(ws + 64 + (size_t)NZB * NPTS * 4 +
                       (size_t)SPL * NZB * NPTS * 4);

  dim3 grid_nn(NPTS / QBLK, SPL, NZB);
  nn_partial_kernel<SPL><<<grid_nn, 256, 0, stream>>>(pw, pp, tw, tp, part_d,
                                                      part_t);
  nn_merge_rescan_kernel<SPL><<<(NZB * NPTS) / 64, 1024, 0, stream>>>(
      pw, pp, tw, tp, part_d, part_t, idx_all, acc);

  dim3 grid_loss(BN / 256, 4);
  loss_kernel<<<grid_loss, 256, 0, stream>>>(pw, pp, tw, tp, ipw, itw, ipp, itp,
                                             idx_all, acc);
  finalize_kernel<<<1, 1, 0, stream>>>(acc, out);
}

extern "C" void kernel_launch(void* const* d_in, const int* in_sizes, int n_in,
                              void* d_out, int out_size, void* d_ws, size_t ws_size,
                              hipStream_t stream) {
  const float* pw = (const float*)d_in[0];
  const float* pp = (const float*)d_in[1];
  const float* tw = (const float*)d_in[2];
  const float* tp = (const float*)d_in[3];
  const int* ipw = (const int*)d_in[4];
  const int* itw = (const int*)d_in[5];
  const int* ipp = (const int*)d_in[6];
  const int* itp = (const int*)d_in[7];
  char* ws = (char*)d_ws;
  float* out = (float*)d_out;

  // ws need per SPL: 64 + idx(512K) + part_d(SPL*512K) + part_t(SPL*128K)
  const size_t base_need = 64 + (size_t)NZB * NPTS * 4;
  const size_t per_spl = (size_t)NZB * NPTS * 5;
  if (ws_size >= base_need + 32 * per_spl) {
    run_pipeline<32>(pw, pp, tw, tp, ipw, itw, ipp, itp, ws, out, stream);
  } else if (ws_size >= base_need + 16 * per_spl) {
    run_pipeline<16>(pw, pp, tw, tp, ipw, itw, ipp, itp, ws, out, stream);
  } else {
    run_pipeline<8>(pw, pp, tw, tp, ipw, itw, ipp, itp, ws, out, stream);
  }
}

// Round 9
// 179.486 us; speedup vs baseline: 1.2384x; 1.1022x over previous
//
#include <hip/hip_runtime.h>
#include <math.h>

// Problem constants (reference: B=4, N=8192, points are [B,N,3] fp32)
#define BATCH 4
#define NPTS 8192
#define BN (BATCH * NPTS)
#define NZB 16                 // 4 searches x 4 batches
#define QK 8                   // queries per lane in the scan
#define QBLK (256 * QK)        // 2048 queries per scan block
#define SUBT 64                // provenance subtile (rescan covers this many)

// Workspace: [0] double acc | [8] uint ticket | [64] int idx_all[NZB*NPTS]
//            [64+512K] float part_d[SPL][NZB*NPTS]
//            [after]   u8    part_t[SPL][NZB*NPTS]  (global subtile id, <128)

__device__ __forceinline__ void pick_ab(int z, const float* pw, const float* pp,
                                        const float* tw, const float* tp,
                                        const float** qa, const float** cb) {
  if (z == 0)      { *qa = pw; *cb = pp; }
  else if (z == 1) { *qa = pp; *cb = pw; }
  else if (z == 2) { *qa = tw; *cb = tp; }
  else             { *qa = tp; *cb = tw; }
}

// ---------------------------------------------------------------------------
// Pass 1 (proven, ~85.5us): min-distance scan + subtile provenance.
// ~3.6 cyc/wave-instr vs measured practical fp32 issue ~3.05 — near ceiling.
// ---------------------------------------------------------------------------
template <int SPL>
__global__ __launch_bounds__(256, 4) void nn_partial_kernel(
    const float* __restrict__ pw, const float* __restrict__ pp,
    const float* __restrict__ tw, const float* __restrict__ tp,
    float* __restrict__ part_d, unsigned char* __restrict__ part_t) {
  constexpr int SLICE = NPTS / SPL;
  constexpr int NSUB = SLICE / SUBT;
  __shared__ float4 sh[SLICE];

  const int zb = blockIdx.z;
  const int z = zb >> 2;
  const int b = zb & 3;
  const float* qa;
  const float* cb;
  pick_ab(z, pw, pp, tw, tp, &qa, &cb);

  const int tid = threadIdx.x;
  const int cslice = blockIdx.y * SLICE;
  const float* cbb = cb + (size_t)b * NPTS * 3;

  // Stage slice as (x,y,z,||b||^2); formulas must match rescan exactly.
  for (int m = tid; m < SLICE; m += 256) {
    const float* c = cbb + (size_t)(cslice + m) * 3;
    const float bx = c[0], by = c[1], bz = c[2];
    sh[m] = make_float4(bx, by, bz, fmaf(bx, bx, fmaf(by, by, bz * bz)));
  }
  __syncthreads();

  const int qbase = blockIdx.x * QBLK;
  float qx[QK], qy[QK], qz[QK], dmin[QK];
  int tile[QK];
  #pragma unroll
  for (int k = 0; k < QK; ++k) {
    const int n = qbase + tid + k * 256;
    const float* q = qa + ((size_t)b * NPTS + n) * 3;
    qx[k] = -2.0f * q[0];
    qy[k] = -2.0f * q[1];
    qz[k] = -2.0f * q[2];
    dmin[k] = INFINITY;
    tile[k] = 0;
  }

  for (int sub = 0; sub < NSUB; ++sub) {
    float pre[QK];
    #pragma unroll
    for (int k = 0; k < QK; ++k) pre[k] = dmin[k];

    const int cb0 = sub * SUBT;
    #pragma unroll 2
    for (int p = 0; p < SUBT / 2; ++p) {
      const float4 c0 = sh[cb0 + 2 * p];
      const float4 c1 = sh[cb0 + 2 * p + 1];
      float t0[QK], t1[QK];
      #pragma unroll
      for (int k = 0; k < QK; ++k)
        t0[k] = fmaf(qx[k], c0.x, fmaf(qy[k], c0.y, fmaf(qz[k], c0.z, c0.w)));
      #pragma unroll
      for (int k = 0; k < QK; ++k)
        t1[k] = fmaf(qx[k], c1.x, fmaf(qy[k], c1.y, fmaf(qz[k], c1.z, c1.w)));
      #pragma unroll
      for (int k = 0; k < QK; ++k)
        dmin[k] = fminf(fminf(t0[k], t1[k]), dmin[k]);   // v_min3_f32
    }
    const int g = blockIdx.y * NSUB + sub;   // global subtile id, [0,128)
    #pragma unroll
    for (int k = 0; k < QK; ++k)
      tile[k] = (dmin[k] < pre[k]) ? g : tile[k];  // strict <: first-min kept
  }

  #pragma unroll
  for (int k = 0; k < QK; ++k) {
    const int n = qbase + tid + k * 256;
    const size_t o = (size_t)blockIdx.y * (NZB * NPTS) + (size_t)zb * NPTS + n;
    part_d[o] = dmin[k];
    part_t[o] = (unsigned char)tile[k];
  }
}

// ---------------------------------------------------------------------------
// Pass 2 (proven R8 shape): fused merge + rescan. Block = 1024 (16 waves)
// covers 64 consecutive queries. Also zeroes acc + ticket for pass 3.
// ---------------------------------------------------------------------------
template <int SPL>
__global__ __launch_bounds__(1024) void nn_merge_rescan_kernel(
    const float* __restrict__ pw, const float* __restrict__ pp,
    const float* __restrict__ tw, const float* __restrict__ tp,
    const float* __restrict__ part_d, const unsigned char* __restrict__ part_t,
    int* __restrict__ idx_all, double* __restrict__ acc,
    unsigned int* __restrict__ ticket) {
  __shared__ float md[16][64];
  __shared__ int mg[16][64];
  __shared__ float sdq[64];
  __shared__ int sgq[64];

  if (blockIdx.x == 0 && threadIdx.x == 0) { *acc = 0.0; *ticket = 0u; }

  const int tid = threadIdx.x;
  const int wv = tid >> 6;          // wave id, 0..15
  const int lane = tid & 63;
  const int qid0 = blockIdx.x * 64;

  // --- Merge phase: coalesced plane loads, per-wave partial lexmin ---
  {
    float bd = INFINITY;
    int bg = 0x7fffffff;
    for (int s = wv; s < SPL; s += 16) {
      const size_t o = (size_t)s * (NZB * NPTS) + qid0 + lane;  // 64 consecutive
      const float d = part_d[o];
      const int g = part_t[o];
      if (d < bd || (d == bd && g < bg)) { bd = d; bg = g; }
    }
    md[wv][lane] = bd;
    mg[wv][lane] = bg;
  }
  __syncthreads();
  if (wv == 0) {                    // wave 0: final 16-way reduce per query
    float bd = md[0][lane];
    int bg = mg[0][lane];
    #pragma unroll
    for (int v = 1; v < 16; ++v) {
      const float d = md[v][lane];
      const int g = mg[v][lane];
      if (d < bd || (d == bd && g < bg)) { bd = d; bg = g; }
    }
    sdq[lane] = bd;
    sgq[lane] = bg;
  }
  __syncthreads();

  // --- Rescan phase: wave v -> queries v*4 .. v*4+3 ---
  const int zb = qid0 >> 13;        // uniform per block
  const int z = zb >> 2;
  const int b = zb & 3;
  const float* qa;
  const float* cb;
  pick_ab(z, pw, pp, tw, tp, &qa, &cb);
  const float* qb0 = qa + (size_t)b * NPTS * 3;
  const float* cbb = cb + (size_t)b * NPTS * 3;
  const int n0 = qid0 & (NPTS - 1);

  #pragma unroll
  for (int j = 0; j < 4; ++j) {
    const int lq = wv * 4 + j;
    const float best_d = sdq[lq];   // LDS broadcast
    const int best_g = sgq[lq];
    const float* q = qb0 + (size_t)(n0 + lq) * 3;   // wave-uniform 12B
    const float qx = -2.0f * q[0];
    const float qy = -2.0f * q[1];
    const float qz = -2.0f * q[2];
    const int m = best_g * SUBT + lane;             // contiguous across wave
    const float* c = cbb + (size_t)m * 3;
    const float bx = c[0], by = c[1], bz = c[2];
    const float b2 = fmaf(bx, bx, fmaf(by, by, bz * bz));
    const float dd = fmaf(qx, bx, fmaf(qy, by, fmaf(qz, bz, b2)));
    const unsigned long long hit = __ballot(dd == best_d);
    if (lane == 0)
      idx_all[qid0 + lq] = best_g * SUBT + (__ffsll((long long)hit) - 1);
  }
}

// ---------------------------------------------------------------------------
// Pass 3: loss (4 MSN terms split across blockIdx.y) + fused finalize.
// One acc-atomic per block; ordering via the atomic's RETURN VALUE (forces
// completion at the device coherence point) before the ticket bump — no
// __threadfence needed. Last of the 512 blocks reads acc and writes out.
// loss = 0.25 * (sum of 4 squared-norm sums) / (B*N)
// ---------------------------------------------------------------------------
__device__ __forceinline__ float3 ld3(const float* __restrict__ p, int i) {
  const float* q = p + (size_t)i * 3;
  return make_float3(q[0], q[1], q[2]);
}

__device__ __forceinline__ float diff_nrm2(float3 a1, float3 a2, float3 b1, float3 b2) {
  const float x = (a1.x - a2.x) - (b1.x - b2.x);
  const float y = (a1.y - a2.y) - (b1.y - b2.y);
  const float z = (a1.z - a2.z) - (b1.z - b2.z);
  return fmaf(x, x, fmaf(y, y, z * z));
}

__global__ __launch_bounds__(256) void loss_final_kernel(
    const float* __restrict__ pw, const float* __restrict__ pp,
    const float* __restrict__ tw, const float* __restrict__ tp,
    const int* __restrict__ ipw, const int* __restrict__ itw,
    const int* __restrict__ ipp, const int* __restrict__ itp,
    const int* __restrict__ idx_all, double* __restrict__ acc,
    unsigned int* __restrict__ ticket, float* __restrict__ out) {
  __shared__ double sd[4];

  const int gid = blockIdx.x * 256 + threadIdx.x;  // [0, B*N)
  const int term = blockIdx.y;
  const int b = gid >> 13;
  const int n = gid & (NPTS - 1);
  const int base = b * NPTS;

  const float* PW = pw + (size_t)base * 3;
  const float* PP = pp + (size_t)base * 3;
  const float* TW = tw + (size_t)base * 3;
  const float* TP = tp + (size_t)base * 3;
  const int* I1P = idx_all + (0 * BATCH + b) * NPTS;  // NN pial for white (pred)
  const int* I2P = idx_all + (1 * BATCH + b) * NPTS;  // NN white for pial (pred)
  const int* I1T = idx_all + (2 * BATCH + b) * NPTS;  // NN pial for white (true)
  const int* I2T = idx_all + (3 * BATCH + b) * NPTS;  // NN white for pial (true)

  float sv;
  if (term == 0) {        // msn(yp_inner, yt_inner[i_pred_white])
    const int j = ipw[base + n];
    sv = diff_nrm2(ld3(PP, I1P[n]), ld3(PW, n), ld3(TP, I1T[j]), ld3(TW, j));
  } else if (term == 1) { // msn(yp_inner[i_true_white], yt_inner)
    const int k = itw[base + n];
    sv = diff_nrm2(ld3(PP, I1P[k]), ld3(PW, k), ld3(TP, I1T[n]), ld3(TW, n));
  } else if (term == 2) { // msn(yp_outer, yt_outer[i_pred_pial])
    const int j = ipp[base + n];
    sv = diff_nrm2(ld3(PP, n), ld3(PW, I2P[n]), ld3(TP, j), ld3(TW, I2T[j]));
  } else {                // msn(yp_outer[i_true_pial], yt_outer)
    const int k = itp[base + n];
    sv = diff_nrm2(ld3(PP, k), ld3(PW, I2P[k]), ld3(TP, n), ld3(TW, I2T[n]));
  }

  // Wave shuffle-reduce -> LDS -> single block sum.
  double ds = (double)sv;
  #pragma unroll
  for (int o = 32; o > 0; o >>= 1) ds += __shfl_down(ds, o, 64);
  if ((threadIdx.x & 63) == 0) sd[threadIdx.x >> 6] = ds;
  __syncthreads();

  if (threadIdx.x == 0) {
    const double bsum = sd[0] + sd[1] + sd[2] + sd[3];
    const double old = atomicAdd(acc, bsum);   // return forces completion
    // Data-dependency on 'old' orders the ticket bump after the acc add.
    const unsigned int inc = 1u + (unsigned int)(((unsigned long long)
                             __double_as_longlong(old)) & 0ull);
    const unsigned int total = gridDim.x * gridDim.y;   // 512
    const unsigned int t = atomicAdd(ticket, inc);
    if (t == total - 1u) {
      const double fin = atomicAdd(acc, 0.0);  // atomic read of the full sum
      out[0] = (float)(0.25 * fin / (double)BN);
    }
  }
}

// ---------------------------------------------------------------------------
template <int SPL>
static void run_pipeline(const float* pw, const float* pp, const float* tw,
                         const float* tp, const int* ipw, const int* itw,
                         const int* ipp, const int* itp, char* ws, float* out,
                         hipStream_t stream) {
  double* acc = (double*)ws;
  unsigned int* ticket = (unsigned int*)(ws + 8);
  int* idx_all = (int*)(ws + 64);
  float* part_d = (float*)(ws + 64 + (size_t)NZB * NPTS * 4);
  unsigned char* part_t =
      (unsigned char*)(ws + 64 + (size_t)NZB * NPTS * 4 +
                       (size_t)SPL * NZB * NPTS * 4);

  dim3 grid_nn(NPTS / QBLK, SPL, NZB);
  nn_partial_kernel<SPL><<<grid_nn, 256, 0, stream>>>(pw, pp, tw, tp, part_d,
                                                      part_t);
  nn_merge_rescan_kernel<SPL><<<(NZB * NPTS) / 64, 1024, 0, stream>>>(
      pw, pp, tw, tp, part_d, part_t, idx_all, acc, ticket);

  dim3 grid_loss(BN / 256, 4);
  loss_final_kernel<<<grid_loss, 256, 0, stream>>>(
      pw, pp, tw, tp, ipw, itw, ipp, itp, idx_all, acc, ticket, out);
}

extern "C" void kernel_launch(void* const* d_in, const int* in_sizes, int n_in,
                              void* d_out, int out_size, void* d_ws, size_t ws_size,
                              hipStream_t stream) {
  const float* pw = (const float*)d_in[0];
  const float* pp = (const float*)d_in[1];
  const float* tw = (const float*)d_in[2];
  const float* tp = (const float*)d_in[3];
  const int* ipw = (const int*)d_in[4];
  const int* itw = (const int*)d_in[5];
  const int* ipp = (const int*)d_in[6];
  const int* itp = (const int*)d_in[7];
  char* ws = (char*)d_ws;
  float* out = (float*)d_out;

  // ws need per SPL: 64 + idx(512K) + part_d(SPL*512K) + part_t(SPL*128K)
  const size_t base_need = 64 + (size_t)NZB * NPTS * 4;
  const size_t per_spl = (size_t)NZB * NPTS * 5;
  if (ws_size >= base_need + 32 * per_spl) {
    run_pipeline<32>(pw, pp, tw, tp, ipw, itw, ipp, itp, ws, out, stream);
  } else if (ws_size >= base_need + 16 * per_spl) {
    run_pipeline<16>(pw, pp, tw, tp, ipw, itw, ipp, itp, ws, out, stream);
  } else {
    run_pipeline<8>(pw, pp, tw, tp, ipw, itw, ipp, itp, ws, out, stream);
  }
}